// Round 2
// baseline (1385.736 us; speedup 1.0000x reference)
//
#include <hip/hip_runtime.h>
#include <math.h>

// f32 I/O, f64 accumulation everywhere (bit-exact vs np-f64 ref at f32
// materialization points — absmax 0.0 R4-R10). Workspace 96 MiB:
// A(16,777,216 f32) + B(8,388,608 f32); boxes/scores in dead x1 space.
//
// R12: R11 (f64 MFMA implicit-GEMM for L2-L4) with the CORRECT f64 C/D
// fragment layout. v_mfma_f64_16x16x4 is the one CDNA MFMA whose C/D
// grouping is register-major: row = 4*reg + (lane>>4)  (CK xdlops
// group_size=1), NOT the f32-family row = 4*(lane>>4)+reg that R11 used
// (that bug scrambled pooling pairs -> absmax 497). Horizontal 2x2-pool
// partner (x, x^1) therefore lives in lane^16 -> one __shfl_xor(16).
// A[i=l%16][k=l/16], B[k=l/16][j=l%16] unchanged (standard 4-input-blk).

constexpr int TOPK_N = 200;

typedef double f64x4 __attribute__((ext_vector_type(4)));

// ---------------------------------------------------------------------------
// L1 only (CIN=3): R10 VALU-f64 tiled fused conv+bias+relu+pool, pipelined.
// Block = 256 threads = 16x16 pooled outputs (32x32 pre-pool), CO_BLK=8.
// ---------------------------------------------------------------------------
template <int CIN, int CI_BLK, int CO_BLK>
__launch_bounds__(256)
__global__ void conv_relu_pool_pipe(const float* __restrict__ in,
                                    const float* __restrict__ wgt,
                                    const float* __restrict__ bias,
                                    float* __restrict__ out,
                                    int Hin, int Win, int Cout) {
    constexpr int SPATIAL = 34 * 34;               // 1156
    constexpr int SSLOT = (SPATIAL + 255) / 256;   // 5
    constexpr int NW = CI_BLK * 9 * CO_BLK;        // weights per chunk
    constexpr int NCHUNK = CIN / CI_BLK;
    const int Hp = Hin >> 1, Wp = Win >> 1;
    const int coChunks = Cout / CO_BLK;
    const int b  = blockIdx.z / coChunks;
    const int cz = blockIdx.z % coChunks;
    const int tid = threadIdx.x;
    const int tx = tid & 15, ty = tid >> 4;
    const int px = (blockIdx.x << 4) + tx;
    const int py = (blockIdx.y << 4) + ty;
    const int iy0 = (blockIdx.y << 5) - 1;
    const int ix0 = (blockIdx.x << 5) - 1;

    __shared__ float  s_in[2][CI_BLK * SPATIAL];
    __shared__ double s_w[2][NW];

    int soff[SSLOT];
#pragma unroll
    for (int s = 0; s < SSLOT; ++s) {
        const int cell = tid + s * 256;
        int g = -1;
        if (cell < SPATIAL) {
            const int ly = cell / 34, lx = cell - ly * 34;
            const int iy = iy0 + ly, ix = ix0 + lx;
            if ((unsigned)iy < (unsigned)Hin && (unsigned)ix < (unsigned)Win)
                g = iy * Win + ix;
        }
        soff[s] = g;
    }
    int wg = -1;
    if (tid < NW) {
        const int co   = tid & (CO_BLK - 1);
        const int rest = tid / CO_BLK;
        const int k    = rest % 9;
        const int ci   = rest / 9;
        wg = ((cz * CO_BLK + co) * CIN + ci) * 9 + k;
    }
    const size_t HW = (size_t)Hin * Win;
    const float* in_b = in + (size_t)b * CIN * HW;

    double acc[CO_BLK][4];
#pragma unroll
    for (int co = 0; co < CO_BLK; ++co)
#pragma unroll
        for (int p = 0; p < 4; ++p) acc[co][p] = 0.0;

    float rin[CI_BLK][SSLOT];
    float rw = 0.f;

#pragma unroll
    for (int ci = 0; ci < CI_BLK; ++ci) {
        const float* src = in_b + ci * HW;
#pragma unroll
        for (int s = 0; s < SSLOT; ++s) {
            const int cell = tid + s * 256;
            float v = 0.f;
            if (cell < SPATIAL) { const int g = soff[s]; if (g >= 0) v = src[g]; }
            rin[ci][s] = v;
        }
    }
    if (tid < NW) rw = wgt[wg];
#pragma unroll
    for (int ci = 0; ci < CI_BLK; ++ci)
#pragma unroll
        for (int s = 0; s < SSLOT; ++s) {
            const int cell = tid + s * 256;
            if (cell < SPATIAL) s_in[0][ci * SPATIAL + cell] = rin[ci][s];
        }
    if (tid < NW) s_w[0][tid] = (double)rw;
    __syncthreads();

    for (int c = 0; c < NCHUNK; ++c) {
        const int buf = c & 1;
        if (c + 1 < NCHUNK) {
            const int c0n = (c + 1) * CI_BLK;
#pragma unroll
            for (int ci = 0; ci < CI_BLK; ++ci) {
                const float* src = in_b + (c0n + ci) * HW;
#pragma unroll
                for (int s = 0; s < SSLOT; ++s) {
                    const int cell = tid + s * 256;
                    float v = 0.f;
                    if (cell < SPATIAL) { const int g = soff[s]; if (g >= 0) v = src[g]; }
                    rin[ci][s] = v;
                }
            }
            if (tid < NW) rw = wgt[wg + c0n * 9];
        }
#pragma unroll 1
        for (int ci = 0; ci < CI_BLK; ++ci) {
            const float* tile = &s_in[buf][ci * SPATIAL];
            double win[4][4];
#pragma unroll
            for (int iy = 0; iy < 4; ++iy) {
                float2 r0 = *(const float2*)&tile[(2 * ty + iy) * 34 + 2 * tx];
                float2 r1 = *(const float2*)&tile[(2 * ty + iy) * 34 + 2 * tx + 2];
                win[iy][0] = (double)r0.x; win[iy][1] = (double)r0.y;
                win[iy][2] = (double)r1.x; win[iy][3] = (double)r1.y;
            }
#pragma unroll
            for (int k = 0; k < 9; ++k) {
                const int ky = k / 3, kx = k % 3;
                const double* wp = &s_w[buf][(ci * 9 + k) * CO_BLK];
                double w[CO_BLK];
#pragma unroll
                for (int co = 0; co < CO_BLK; ++co) w[co] = wp[co];
#pragma unroll
                for (int p = 0; p < 4; ++p) {
                    const double v = win[(p >> 1) + ky][(p & 1) + kx];
#pragma unroll
                    for (int co = 0; co < CO_BLK; ++co)
                        acc[co][p] = fma(v, w[co], acc[co][p]);
                }
            }
        }
        if (c + 1 < NCHUNK) {
#pragma unroll
            for (int ci = 0; ci < CI_BLK; ++ci)
#pragma unroll
                for (int s = 0; s < SSLOT; ++s) {
                    const int cell = tid + s * 256;
                    if (cell < SPATIAL) s_in[buf ^ 1][ci * SPATIAL + cell] = rin[ci][s];
                }
            if (tid < NW) s_w[buf ^ 1][tid] = (double)rw;
            __syncthreads();
        }
    }

#pragma unroll
    for (int co = 0; co < CO_BLK; ++co) {
        const double bd = (double)bias[cz * CO_BLK + co];
        const float e0 = fmaxf((float)(acc[co][0] + bd), 0.f);
        const float e1 = fmaxf((float)(acc[co][1] + bd), 0.f);
        const float e2 = fmaxf((float)(acc[co][2] + bd), 0.f);
        const float e3 = fmaxf((float)(acc[co][3] + bd), 0.f);
        out[((size_t)(b * Cout + cz * CO_BLK + co) * Hp + py) * Wp + px] =
            fmaxf(fmaxf(e0, e1), fmaxf(e2, e3));
    }
}

// ---------------------------------------------------------------------------
// L2-L4: implicit-GEMM conv via v_mfma_f64_16x16x4 (R12).
// Block = 256 thr = 4 waves; tile = 32x8 pre-pool spatial x 32 cout.
// Wave w: pre-pool rows {2w,2w+1}; M-frag = 16-wide x-strip (2 per row),
// N-frag = 16 cout (2 per block). acc = 4 Mfrag x 2 Nfrag D-tiles (64 VGPR).
// Layouts (CK xdlops, f64 has group_size=1):
//   A lane l -> A[i=l&15][k=l>>4];  B lane l -> B[k=l>>4][j=l&15];
//   D lane l reg r -> D[row = 4*r + (l>>4)][col = l&15]   (REGISTER-major!)
// => within a lane, reg r holds x = 4r + l4 (stride 4); the 2x2-pool
// x-partner (x^1) is in lane^16 -> vertical pool intra-thread (dy in m),
// horizontal pool via __shfl_xor(16), even-l4 lanes store scalars.
// LDS: in 2x8x360 + w 2x8x296 f32 = 41984 B (3 blk/CU). Strides 360/296 are
// ==8 mod 32: the 4 k-groups start 8 banks apart -> every bank exactly
// 2-way on ds_read = free (m136). R10 prefetch->compute->commit pipeline.
// ---------------------------------------------------------------------------
template <int CIN>
__launch_bounds__(256)
__global__ void conv_mfma_f64(const float* __restrict__ in,
                              const float* __restrict__ wgt,
                              const float* __restrict__ bias,
                              float* __restrict__ out,
                              int Hin, int Win, int Cout) {
    constexpr int TW = 34;               // halo tile width  (32 + 2)
    constexpr int CELLS = 34 * 10;       // halo tile cells  (8 + 2 rows)
    constexpr int CH = 360;              // padded per-ci LDS stride (==8 mod 32)
    constexpr int CI_CHUNK = 8;
    constexpr int NCHUNK = CIN / CI_CHUNK;
    constexpr int WST = 296;             // 9*32 + 8 pad      (==8 mod 32)

    const int Hp = Hin >> 1, Wp = Win >> 1;
    const int coChunks = Cout >> 5;
    const int b   = blockIdx.z / coChunks;
    const int cob = blockIdx.z % coChunks;
    const int tid = threadIdx.x;
    const int wv  = tid >> 6;
    const int l15 = tid & 15;
    const int l4  = (tid >> 4) & 3;
    const int x0 = blockIdx.x << 5;      // pre-pool tile origin x (32 wide)
    const int y0 = blockIdx.y << 3;      // pre-pool tile origin y (8 tall)

    __shared__ float s_in[2][CI_CHUNK * CH];
    __shared__ float s_w[2][CI_CHUNK * WST];

    // ---- chunk-invariant staging geometry ----
    int soff[2];
#pragma unroll
    for (int s = 0; s < 2; ++s) {
        const int cell = tid + s * 256;
        int g = -1;
        if (cell < CELLS) {
            const int ly = cell / TW, lx = cell - ly * TW;
            const int iy = y0 - 1 + ly, ix = x0 - 1 + lx;
            if ((unsigned)iy < (unsigned)Hin && (unsigned)ix < (unsigned)Win)
                g = iy * Win + ix;
        }
        soff[s] = g;
    }
    int wgoff[9], lwoff[9];              // 2304 = 9*256 weight slots exactly
#pragma unroll
    for (int s = 0; s < 9; ++s) {
        const int idx  = s * 256 + tid;
        const int co_l = idx & 31;
        const int r    = idx >> 5;       // 0..71
        const int tap  = r % 9;
        const int ci_l = r / 9;          // 0..7
        wgoff[s] = ((cob * 32 + co_l) * CIN + ci_l) * 9 + tap;
        lwoff[s] = ci_l * WST + tap * 32 + co_l;
    }
    const size_t HW = (size_t)Hin * Win;
    const float* in_b = in + (size_t)b * CIN * HW;

    // ---- per-wave mfma read bases (f32 element indices) ----
    int abase[4];
#pragma unroll
    for (int m = 0; m < 4; ++m) {
        const int dy = m >> 1, xh = m & 1;
        abase[m] = l4 * CH + (2 * wv + dy) * TW + xh * 16 + l15;
    }
    const int bbase0 = l4 * WST + l15;
    const int bbase1 = l4 * WST + 16 + l15;

    f64x4 acc[4][2];
#pragma unroll
    for (int m = 0; m < 4; ++m)
#pragma unroll
        for (int n = 0; n < 2; ++n)
#pragma unroll
            for (int j = 0; j < 4; ++j) acc[m][n][j] = 0.0;

    float rin[CI_CHUNK][2];
    float rwt[9];

    // ---- prologue: fetch + commit chunk 0 ----
#pragma unroll
    for (int ci = 0; ci < CI_CHUNK; ++ci) {
        const float* src = in_b + (size_t)ci * HW;
        rin[ci][0] = (soff[0] >= 0) ? src[soff[0]] : 0.f;
        rin[ci][1] = (soff[1] >= 0) ? src[soff[1]] : 0.f;
    }
#pragma unroll
    for (int s = 0; s < 9; ++s) rwt[s] = wgt[wgoff[s]];
#pragma unroll
    for (int ci = 0; ci < CI_CHUNK; ++ci) {
        s_in[0][ci * CH + tid] = rin[ci][0];
        if (tid < CELLS - 256) s_in[0][ci * CH + tid + 256] = rin[ci][1];
    }
#pragma unroll
    for (int s = 0; s < 9; ++s) s_w[0][lwoff[s]] = rwt[s];
    __syncthreads();

#pragma unroll 2
    for (int c = 0; c < NCHUNK; ++c) {
        const int buf = c & 1;
        // ---- issue next chunk's global loads (land under the mfmas) ----
        if (c + 1 < NCHUNK) {
            const int c0n = (c + 1) * CI_CHUNK;
#pragma unroll
            for (int ci = 0; ci < CI_CHUNK; ++ci) {
                const float* src = in_b + (size_t)(c0n + ci) * HW;
                rin[ci][0] = (soff[0] >= 0) ? src[soff[0]] : 0.f;
                rin[ci][1] = (soff[1] >= 0) ? src[soff[1]] : 0.f;
            }
#pragma unroll
            for (int s = 0; s < 9; ++s) rwt[s] = wgt[wgoff[s] + c0n * 9];
        }
        // ---- compute: 9 taps x 2 ci4-groups x 8 D-tiles = 144 mfma ----
        {
            const float* ti = &s_in[buf][0];
            const float* tw = &s_w[buf][0];
#pragma unroll
            for (int tap = 0; tap < 9; ++tap) {
                const int ky = tap / 3, kx = tap % 3;
#pragma unroll
                for (int g = 0; g < 2; ++g) {
                    const int ka = g * 4 * CH + ky * TW + kx;
                    const int kb = g * 4 * WST + tap * 32;
                    const double b0 = (double)tw[bbase0 + kb];
                    const double b1 = (double)tw[bbase1 + kb];
                    const double a0 = (double)ti[abase[0] + ka];
                    const double a1 = (double)ti[abase[1] + ka];
                    const double a2 = (double)ti[abase[2] + ka];
                    const double a3 = (double)ti[abase[3] + ka];
                    acc[0][0] = __builtin_amdgcn_mfma_f64_16x16x4f64(a0, b0, acc[0][0], 0, 0, 0);
                    acc[0][1] = __builtin_amdgcn_mfma_f64_16x16x4f64(a0, b1, acc[0][1], 0, 0, 0);
                    acc[1][0] = __builtin_amdgcn_mfma_f64_16x16x4f64(a1, b0, acc[1][0], 0, 0, 0);
                    acc[1][1] = __builtin_amdgcn_mfma_f64_16x16x4f64(a1, b1, acc[1][1], 0, 0, 0);
                    acc[2][0] = __builtin_amdgcn_mfma_f64_16x16x4f64(a2, b0, acc[2][0], 0, 0, 0);
                    acc[2][1] = __builtin_amdgcn_mfma_f64_16x16x4f64(a2, b1, acc[2][1], 0, 0, 0);
                    acc[3][0] = __builtin_amdgcn_mfma_f64_16x16x4f64(a3, b0, acc[3][0], 0, 0, 0);
                    acc[3][1] = __builtin_amdgcn_mfma_f64_16x16x4f64(a3, b1, acc[3][1], 0, 0, 0);
                }
            }
        }
        // ---- commit prefetched regs to the other buffer, one barrier ----
        if (c + 1 < NCHUNK) {
#pragma unroll
            for (int ci = 0; ci < CI_CHUNK; ++ci) {
                s_in[buf ^ 1][ci * CH + tid] = rin[ci][0];
                if (tid < CELLS - 256) s_in[buf ^ 1][ci * CH + tid + 256] = rin[ci][1];
            }
#pragma unroll
            for (int s = 0; s < 9; ++s) s_w[buf ^ 1][lwoff[s]] = rwt[s];
            __syncthreads();
        }
    }

    // ---- epilogue: bias (f64) -> relu (f32) -> 2x2 maxpool -> store.
    // Reg r of acc[m][n] holds pre-pool x = x0 + xh*16 + 4r + l4, y = y0+2wv+dy.
    // Vertical pool: intra-thread (m pairs). Horizontal pool: partner x^1 is
    // lane^16 (l4^1, same r) -> __shfl_xor(16). Even-l4 lanes store.
    // Same f64->f32 materialization formula as R10 (max-tree order commutes).
    const int yp = (y0 >> 1) + wv;
#pragma unroll
    for (int n = 0; n < 2; ++n) {
        const int co = cob * 32 + n * 16 + l15;
        const double bd = (double)bias[co];
        float* orow = out + (((size_t)b * Cout + co) * Hp + yp) * Wp;
#pragma unroll
        for (int xh = 0; xh < 2; ++xh) {
#pragma unroll
            for (int r = 0; r < 4; ++r) {
                const float e0 = fmaxf((float)(acc[xh][n][r]     + bd), 0.f);
                const float e1 = fmaxf((float)(acc[2 + xh][n][r] + bd), 0.f);
                float v = fmaxf(e0, e1);                 // vertical pool
                const float p = __shfl_xor(v, 16, 64);   // horizontal partner
                v = fmaxf(v, p);
                if ((l4 & 1) == 0) {
                    const int xp = (x0 >> 1) + xh * 8 + 2 * r + (l4 >> 1);
                    orow[xp] = v;
                }
            }
        }
    }
}

// ---------------------------------------------------------------------------
// Head 1x1 conv (256->5, f64) + decode (f64) -> boxes/scores. 32 blocks.
// ---------------------------------------------------------------------------
__launch_bounds__(256)
__global__ void head_decode_k(const float* __restrict__ x4,
                              const float* __restrict__ wh,
                              const float* __restrict__ bh,
                              float* __restrict__ boxes,
                              float* __restrict__ scores) {
    __shared__ float s_wh[5 * 256];
    const int tid = threadIdx.x;
#pragma unroll
    for (int i = 0; i < 5; ++i) s_wh[i * 256 + tid] = wh[i * 256 + tid];
    __syncthreads();

    const int idx  = blockIdx.x * 256 + tid;  // 0..8191
    const int b    = idx >> 10;
    const int cell = idx & 1023;
    const int gy = cell >> 5, gx = cell & 31;

    double a0 = (double)bh[0], a1 = (double)bh[1], a2 = (double)bh[2],
           a3 = (double)bh[3], a4 = (double)bh[4];
    const float* xp = x4 + b * 262144 + cell;
    for (int ci = 0; ci < 256; ++ci) {
        const double v = (double)xp[ci << 10];
        a0 = fma(v, (double)s_wh[0 * 256 + ci], a0);
        a1 = fma(v, (double)s_wh[1 * 256 + ci], a1);
        a2 = fma(v, (double)s_wh[2 * 256 + ci], a2);
        a3 = fma(v, (double)s_wh[3 * 256 + ci], a3);
        a4 = fma(v, (double)s_wh[4 * 256 + ci], a4);
    }
    const double obj = 1.0 / (1.0 + exp(-a0));
    const double txs = 1.0 / (1.0 + exp(-a1));
    const double tys = 1.0 / (1.0 + exp(-a2));
    const double bw  = exp(a3) * 16.0;
    const double bhh = exp(a4) * 16.0;
    const double cx  = gx * 16.0 + txs * 16.0;
    const double cy  = gy * 16.0 + tys * 16.0;
    float* bp = boxes + idx * 4;
    bp[0] = (float)fmin(fmax(cx - bw * 0.5, 0.0), 511.0);
    bp[1] = (float)fmin(fmax(cy - bhh * 0.5, 0.0), 511.0);
    bp[2] = (float)fmin(fmax(cx + bw * 0.5, 0.0), 511.0);
    bp[3] = (float)fmin(fmax(cy + bhh * 0.5, 0.0), 511.0);
    scores[idx] = (float)obj;
}

// ---------------------------------------------------------------------------
// Per-batch top-200 (bitonic, lax.top_k tie semantics) + greedy NMS + output.
// ---------------------------------------------------------------------------
__launch_bounds__(256)
__global__ void topk_nms_k(const float* __restrict__ boxes,
                           const float* __restrict__ scores,
                           float* __restrict__ out5,
                           float* __restrict__ keep_out) {
    const int b = blockIdx.x, tid = threadIdx.x;
    __shared__ unsigned long long key[1024];
    __shared__ float bx1[TOPK_N], by1[TOPK_N], bx2[TOPK_N], by2[TOPK_N];
    __shared__ float sv[TOPK_N], ar[TOPK_N];
    __shared__ int   kp[TOPK_N];

    for (int i = tid; i < 1024; i += 256) {
        float s = scores[b * 1024 + i];
        float m = (s >= 0.01f) ? s : -1.0f;
        unsigned u = __float_as_uint(m);
        u = (u & 0x80000000u) ? ~u : (u | 0x80000000u);
        key[i] = ((unsigned long long)u << 32) | (unsigned)(1023 - i);
    }
    __syncthreads();

    for (int k = 2; k <= 1024; k <<= 1) {
        for (int j = k >> 1; j > 0; j >>= 1) {
            for (int i = tid; i < 1024; i += 256) {
                int l = i ^ j;
                if (l > i) {
                    unsigned long long a = key[i], c = key[l];
                    bool desc = ((i & k) == 0);
                    bool sw = desc ? (a < c) : (a > c);
                    if (sw) { key[i] = c; key[l] = a; }
                }
            }
            __syncthreads();
        }
    }

    for (int i = tid; i < TOPK_N; i += 256) {
        unsigned long long kk = key[i];
        unsigned u = (unsigned)(kk >> 32);
        unsigned bits = (u & 0x80000000u) ? (u & 0x7FFFFFFFu) : ~u;
        float s = __uint_as_float(bits);
        int src = 1023 - (int)(kk & 0xFFFFFFFFu);
        const float4 bb = *(const float4*)(boxes + (b * 1024 + src) * 4);
        bx1[i] = bb.x; by1[i] = bb.y; bx2[i] = bb.z; by2[i] = bb.w;
        sv[i] = s;
        ar[i] = (bb.z - bb.x) * (bb.w - bb.y);
        kp[i] = (s >= 0.01f) ? 1 : 0;
    }
    __syncthreads();

    for (int i = 0; i < TOPK_N; ++i) {
        if (kp[i]) {
            const float X1 = bx1[i], Y1 = by1[i], X2 = bx2[i], Y2 = by2[i], A = ar[i];
            for (int j = tid; j < TOPK_N; j += 256) {
                if (j > i && kp[j]) {
                    float xx1 = fmaxf(X1, bx1[j]);
                    float yy1 = fmaxf(Y1, by1[j]);
                    float xx2 = fminf(X2, bx2[j]);
                    float yy2 = fminf(Y2, by2[j]);
                    float inter = fmaxf(xx2 - xx1, 0.f) * fmaxf(yy2 - yy1, 0.f);
                    float uni = A + ar[j] - inter;
                    float iou = inter / fmaxf(uni, 1e-6f);
                    if (iou > 0.5f) kp[j] = 0;
                }
            }
        }
        __syncthreads();
    }

    for (int i = tid; i < TOPK_N; i += 256) {
        float kf = kp[i] ? 1.f : 0.f;
        float s  = sv[i];
        float sc = (s >= 0.01f) ? s : 0.f;
        float* op = out5 + (b * TOPK_N + i) * 5;
        op[0] = bx1[i] * kf;
        op[1] = by1[i] * kf;
        op[2] = bx2[i] * kf;
        op[3] = by2[i] * kf;
        op[4] = sc * kf;
        keep_out[b * TOPK_N + i] = kf;
    }
}

extern "C" void kernel_launch(void* const* d_in, const int* in_sizes, int n_in,
                              void* d_out, int out_size, void* d_ws, size_t ws_size,
                              hipStream_t stream) {
    const float* images = (const float*)d_in[0];
    const float* w1 = (const float*)d_in[1];
    const float* b1 = (const float*)d_in[2];
    const float* w2 = (const float*)d_in[3];
    const float* b2 = (const float*)d_in[4];
    const float* w3 = (const float*)d_in[5];
    const float* b3 = (const float*)d_in[6];
    const float* w4 = (const float*)d_in[7];
    const float* b4 = (const float*)d_in[8];
    const float* wh = (const float*)d_in[9];
    const float* bh = (const float*)d_in[10];
    float* out = (float*)d_out;

    float* A    = (float*)d_ws;          // x1 [8,32,256,256] -> x3 [8,128,64,64]
    float* Bbuf = A + 16777216;          // x2 [8,64,128,128] -> x4 [8,256,32,32]
    float* boxes  = A + 8388608;         // dead x1 space: 32768 floats
    float* scores = A + 8388608 + 32768; //  8192 floats

    // L1: 3->32, 512x512 -> 256x256. VALU-f64 template (CIN=3 not mfma-shaped).
    conv_relu_pool_pipe<3, 3, 8><<<dim3(16, 16, 8 * 4), 256, 0, stream>>>(
        images, w1, b1, A, 512, 512, 32);
    // L2: 32->64, 256x256 in. MFMA-f64: grid (Wpre/32, Hpre/8, B*Cout/32).
    conv_mfma_f64<32><<<dim3(8, 32, 8 * 2), 256, 0, stream>>>(
        A, w2, b2, Bbuf, 256, 256, 64);
    // L3: 64->128, 128x128 in.
    conv_mfma_f64<64><<<dim3(4, 16, 8 * 4), 256, 0, stream>>>(
        Bbuf, w3, b3, A, 128, 128, 128);
    // L4: 128->256, 64x64 in.
    conv_mfma_f64<128><<<dim3(2, 8, 8 * 8), 256, 0, stream>>>(
        A, w4, b4, Bbuf, 64, 64, 256);
    // Head + decode: 32 blocks, coalesced
    head_decode_k<<<32, 256, 0, stream>>>(Bbuf, wh, bh, boxes, scores);
    // Top-k + NMS + output
    topk_nms_k<<<8, 256, 0, stream>>>(boxes, scores, out, out + 8 * TOPK_N * 5);
}

// Round 3
// 1211.796 us; speedup vs baseline: 1.1435x; 1.1435x over previous
//
#include <hip/hip_runtime.h>
#include <math.h>

// f32 I/O, f64 accumulation everywhere (bit-exact vs np-f64 ref at f32
// materialization points — absmax 0.0 R4-R10, R12). Workspace 96 MiB.
//
// R13: occupancy fix for the f64-MFMA conv (R12 measured MfmaUtil 57%,
// Occupancy 11.9% = 1 wave/SIMD: unified VGPR+AGPR total >256 capped it).
//  - __launch_bounds__(256, 2): force <=256 unified regs/wave -> 2 blk/CU.
//  - weights staged into LDS as f64 (cvt once at commit, like L1 template):
//    removes 2 cvt_f64_f32 per g-iter from the compute stream, B-loads are
//    one ds_read_b64 (WST=296: 2*296==16 mod 32 -> 4 words/bank = 64-lane
//    b64 minimum, conflict-free). LDS 60928 B <= 80 KB keeps 2 blocks/CU.
// Numerics identical (weights were widened to f64 before mfma either way).

constexpr int TOPK_N = 200;

typedef double f64x4 __attribute__((ext_vector_type(4)));

// ---------------------------------------------------------------------------
// L1 only (CIN=3): R10 VALU-f64 tiled fused conv+bias+relu+pool, pipelined.
// Block = 256 threads = 16x16 pooled outputs (32x32 pre-pool), CO_BLK=8.
// ---------------------------------------------------------------------------
template <int CIN, int CI_BLK, int CO_BLK>
__launch_bounds__(256)
__global__ void conv_relu_pool_pipe(const float* __restrict__ in,
                                    const float* __restrict__ wgt,
                                    const float* __restrict__ bias,
                                    float* __restrict__ out,
                                    int Hin, int Win, int Cout) {
    constexpr int SPATIAL = 34 * 34;               // 1156
    constexpr int SSLOT = (SPATIAL + 255) / 256;   // 5
    constexpr int NW = CI_BLK * 9 * CO_BLK;        // weights per chunk
    constexpr int NCHUNK = CIN / CI_BLK;
    const int Hp = Hin >> 1, Wp = Win >> 1;
    const int coChunks = Cout / CO_BLK;
    const int b  = blockIdx.z / coChunks;
    const int cz = blockIdx.z % coChunks;
    const int tid = threadIdx.x;
    const int tx = tid & 15, ty = tid >> 4;
    const int px = (blockIdx.x << 4) + tx;
    const int py = (blockIdx.y << 4) + ty;
    const int iy0 = (blockIdx.y << 5) - 1;
    const int ix0 = (blockIdx.x << 5) - 1;

    __shared__ float  s_in[2][CI_BLK * SPATIAL];
    __shared__ double s_w[2][NW];

    int soff[SSLOT];
#pragma unroll
    for (int s = 0; s < SSLOT; ++s) {
        const int cell = tid + s * 256;
        int g = -1;
        if (cell < SPATIAL) {
            const int ly = cell / 34, lx = cell - ly * 34;
            const int iy = iy0 + ly, ix = ix0 + lx;
            if ((unsigned)iy < (unsigned)Hin && (unsigned)ix < (unsigned)Win)
                g = iy * Win + ix;
        }
        soff[s] = g;
    }
    int wg = -1;
    if (tid < NW) {
        const int co   = tid & (CO_BLK - 1);
        const int rest = tid / CO_BLK;
        const int k    = rest % 9;
        const int ci   = rest / 9;
        wg = ((cz * CO_BLK + co) * CIN + ci) * 9 + k;
    }
    const size_t HW = (size_t)Hin * Win;
    const float* in_b = in + (size_t)b * CIN * HW;

    double acc[CO_BLK][4];
#pragma unroll
    for (int co = 0; co < CO_BLK; ++co)
#pragma unroll
        for (int p = 0; p < 4; ++p) acc[co][p] = 0.0;

    float rin[CI_BLK][SSLOT];
    float rw = 0.f;

#pragma unroll
    for (int ci = 0; ci < CI_BLK; ++ci) {
        const float* src = in_b + ci * HW;
#pragma unroll
        for (int s = 0; s < SSLOT; ++s) {
            const int cell = tid + s * 256;
            float v = 0.f;
            if (cell < SPATIAL) { const int g = soff[s]; if (g >= 0) v = src[g]; }
            rin[ci][s] = v;
        }
    }
    if (tid < NW) rw = wgt[wg];
#pragma unroll
    for (int ci = 0; ci < CI_BLK; ++ci)
#pragma unroll
        for (int s = 0; s < SSLOT; ++s) {
            const int cell = tid + s * 256;
            if (cell < SPATIAL) s_in[0][ci * SPATIAL + cell] = rin[ci][s];
        }
    if (tid < NW) s_w[0][tid] = (double)rw;
    __syncthreads();

    for (int c = 0; c < NCHUNK; ++c) {
        const int buf = c & 1;
        if (c + 1 < NCHUNK) {
            const int c0n = (c + 1) * CI_BLK;
#pragma unroll
            for (int ci = 0; ci < CI_BLK; ++ci) {
                const float* src = in_b + (c0n + ci) * HW;
#pragma unroll
                for (int s = 0; s < SSLOT; ++s) {
                    const int cell = tid + s * 256;
                    float v = 0.f;
                    if (cell < SPATIAL) { const int g = soff[s]; if (g >= 0) v = src[g]; }
                    rin[ci][s] = v;
                }
            }
            if (tid < NW) rw = wgt[wg + c0n * 9];
        }
#pragma unroll 1
        for (int ci = 0; ci < CI_BLK; ++ci) {
            const float* tile = &s_in[buf][ci * SPATIAL];
            double win[4][4];
#pragma unroll
            for (int iy = 0; iy < 4; ++iy) {
                float2 r0 = *(const float2*)&tile[(2 * ty + iy) * 34 + 2 * tx];
                float2 r1 = *(const float2*)&tile[(2 * ty + iy) * 34 + 2 * tx + 2];
                win[iy][0] = (double)r0.x; win[iy][1] = (double)r0.y;
                win[iy][2] = (double)r1.x; win[iy][3] = (double)r1.y;
            }
#pragma unroll
            for (int k = 0; k < 9; ++k) {
                const int ky = k / 3, kx = k % 3;
                const double* wp = &s_w[buf][(ci * 9 + k) * CO_BLK];
                double w[CO_BLK];
#pragma unroll
                for (int co = 0; co < CO_BLK; ++co) w[co] = wp[co];
#pragma unroll
                for (int p = 0; p < 4; ++p) {
                    const double v = win[(p >> 1) + ky][(p & 1) + kx];
#pragma unroll
                    for (int co = 0; co < CO_BLK; ++co)
                        acc[co][p] = fma(v, w[co], acc[co][p]);
                }
            }
        }
        if (c + 1 < NCHUNK) {
#pragma unroll
            for (int ci = 0; ci < CI_BLK; ++ci)
#pragma unroll
                for (int s = 0; s < SSLOT; ++s) {
                    const int cell = tid + s * 256;
                    if (cell < SPATIAL) s_in[buf ^ 1][ci * SPATIAL + cell] = rin[ci][s];
                }
            if (tid < NW) s_w[buf ^ 1][tid] = (double)rw;
            __syncthreads();
        }
    }

#pragma unroll
    for (int co = 0; co < CO_BLK; ++co) {
        const double bd = (double)bias[cz * CO_BLK + co];
        const float e0 = fmaxf((float)(acc[co][0] + bd), 0.f);
        const float e1 = fmaxf((float)(acc[co][1] + bd), 0.f);
        const float e2 = fmaxf((float)(acc[co][2] + bd), 0.f);
        const float e3 = fmaxf((float)(acc[co][3] + bd), 0.f);
        out[((size_t)(b * Cout + cz * CO_BLK + co) * Hp + py) * Wp + px] =
            fmaxf(fmaxf(e0, e1), fmaxf(e2, e3));
    }
}

// ---------------------------------------------------------------------------
// L2-L4: implicit-GEMM conv via v_mfma_f64_16x16x4 (R13).
// Block = 256 thr = 4 waves; tile = 32x8 pre-pool spatial x 32 cout.
// Layouts (CK xdlops, f64 group_size=1):
//   A lane l -> A[i=l&15][k=l>>4];  B lane l -> B[k=l>>4][j=l&15];
//   D lane l reg r -> D[row = 4*r + (l>>4)][col = l&15]   (REGISTER-major)
// Pooling: vertical intra-thread (m pairs), horizontal via __shfl_xor(16).
// LDS: in f32 2x8x360x4 + w f64 2x8x296x8 = 60928 B (2 blk/CU target).
// __launch_bounds__(256,2): R12 measured 1 wave/SIMD (unified regs > 256);
// 2 waves/SIMD lets the second wave cover ds_read/commit/barrier stalls.
// ---------------------------------------------------------------------------
template <int CIN>
__launch_bounds__(256, 2)
__global__ void conv_mfma_f64(const float* __restrict__ in,
                              const float* __restrict__ wgt,
                              const float* __restrict__ bias,
                              float* __restrict__ out,
                              int Hin, int Win, int Cout) {
    constexpr int TW = 34;               // halo tile width  (32 + 2)
    constexpr int CELLS = 34 * 10;       // halo tile cells  (8 + 2 rows)
    constexpr int CH = 360;              // padded per-ci input stride (f32)
    constexpr int CI_CHUNK = 8;
    constexpr int NCHUNK = CIN / CI_CHUNK;
    constexpr int WST = 296;             // per-ci weight stride (f64 elems)

    const int Hp = Hin >> 1, Wp = Win >> 1;
    const int coChunks = Cout >> 5;
    const int b   = blockIdx.z / coChunks;
    const int cob = blockIdx.z % coChunks;
    const int tid = threadIdx.x;
    const int wv  = tid >> 6;
    const int l15 = tid & 15;
    const int l4  = (tid >> 4) & 3;
    const int x0 = blockIdx.x << 5;      // pre-pool tile origin x (32 wide)
    const int y0 = blockIdx.y << 3;      // pre-pool tile origin y (8 tall)

    __shared__ float  s_in[2][CI_CHUNK * CH];
    __shared__ double s_w[2][CI_CHUNK * WST];

    // ---- chunk-invariant staging geometry ----
    int soff[2];
#pragma unroll
    for (int s = 0; s < 2; ++s) {
        const int cell = tid + s * 256;
        int g = -1;
        if (cell < CELLS) {
            const int ly = cell / TW, lx = cell - ly * TW;
            const int iy = y0 - 1 + ly, ix = x0 - 1 + lx;
            if ((unsigned)iy < (unsigned)Hin && (unsigned)ix < (unsigned)Win)
                g = iy * Win + ix;
        }
        soff[s] = g;
    }
    int wgoff[9], lwoff[9];              // 2304 = 9*256 weight slots exactly
#pragma unroll
    for (int s = 0; s < 9; ++s) {
        const int idx  = s * 256 + tid;
        const int co_l = idx & 31;
        const int r    = idx >> 5;       // 0..71
        const int tap  = r % 9;
        const int ci_l = r / 9;          // 0..7
        wgoff[s] = ((cob * 32 + co_l) * CIN + ci_l) * 9 + tap;
        lwoff[s] = ci_l * WST + tap * 32 + co_l;
    }
    const size_t HW = (size_t)Hin * Win;
    const float* in_b = in + (size_t)b * CIN * HW;

    // ---- per-wave mfma read bases (element indices) ----
    int abase[4];
#pragma unroll
    for (int m = 0; m < 4; ++m) {
        const int dy = m >> 1, xh = m & 1;
        abase[m] = l4 * CH + (2 * wv + dy) * TW + xh * 16 + l15;
    }
    const int bbase0 = l4 * WST + l15;
    const int bbase1 = l4 * WST + 16 + l15;

    f64x4 acc[4][2];
#pragma unroll
    for (int m = 0; m < 4; ++m)
#pragma unroll
        for (int n = 0; n < 2; ++n)
#pragma unroll
            for (int j = 0; j < 4; ++j) acc[m][n][j] = 0.0;

    float rin[CI_CHUNK][2];
    float rwt[9];

    // ---- prologue: fetch + commit chunk 0 ----
#pragma unroll
    for (int ci = 0; ci < CI_CHUNK; ++ci) {
        const float* src = in_b + (size_t)ci * HW;
        rin[ci][0] = (soff[0] >= 0) ? src[soff[0]] : 0.f;
        rin[ci][1] = (soff[1] >= 0) ? src[soff[1]] : 0.f;
    }
#pragma unroll
    for (int s = 0; s < 9; ++s) rwt[s] = wgt[wgoff[s]];
#pragma unroll
    for (int ci = 0; ci < CI_CHUNK; ++ci) {
        s_in[0][ci * CH + tid] = rin[ci][0];
        if (tid < CELLS - 256) s_in[0][ci * CH + tid + 256] = rin[ci][1];
    }
#pragma unroll
    for (int s = 0; s < 9; ++s) s_w[0][lwoff[s]] = (double)rwt[s];
    __syncthreads();

#pragma unroll 2
    for (int c = 0; c < NCHUNK; ++c) {
        const int buf = c & 1;
        // ---- issue next chunk's global loads (land under the mfmas) ----
        if (c + 1 < NCHUNK) {
            const int c0n = (c + 1) * CI_CHUNK;
#pragma unroll
            for (int ci = 0; ci < CI_CHUNK; ++ci) {
                const float* src = in_b + (size_t)(c0n + ci) * HW;
                rin[ci][0] = (soff[0] >= 0) ? src[soff[0]] : 0.f;
                rin[ci][1] = (soff[1] >= 0) ? src[soff[1]] : 0.f;
            }
#pragma unroll
            for (int s = 0; s < 9; ++s) rwt[s] = wgt[wgoff[s] + c0n * 9];
        }
        // ---- compute: 9 taps x 2 ci4-groups x 8 D-tiles = 144 mfma ----
        {
            const float*  ti = &s_in[buf][0];
            const double* tw = &s_w[buf][0];
#pragma unroll
            for (int tap = 0; tap < 9; ++tap) {
                const int ky = tap / 3, kx = tap % 3;
#pragma unroll
                for (int g = 0; g < 2; ++g) {
                    const int ka = g * 4 * CH + ky * TW + kx;
                    const int kb = g * 4 * WST + tap * 32;
                    const double b0 = tw[bbase0 + kb];
                    const double b1 = tw[bbase1 + kb];
                    const double a0 = (double)ti[abase[0] + ka];
                    const double a1 = (double)ti[abase[1] + ka];
                    const double a2 = (double)ti[abase[2] + ka];
                    const double a3 = (double)ti[abase[3] + ka];
                    acc[0][0] = __builtin_amdgcn_mfma_f64_16x16x4f64(a0, b0, acc[0][0], 0, 0, 0);
                    acc[0][1] = __builtin_amdgcn_mfma_f64_16x16x4f64(a0, b1, acc[0][1], 0, 0, 0);
                    acc[1][0] = __builtin_amdgcn_mfma_f64_16x16x4f64(a1, b0, acc[1][0], 0, 0, 0);
                    acc[1][1] = __builtin_amdgcn_mfma_f64_16x16x4f64(a1, b1, acc[1][1], 0, 0, 0);
                    acc[2][0] = __builtin_amdgcn_mfma_f64_16x16x4f64(a2, b0, acc[2][0], 0, 0, 0);
                    acc[2][1] = __builtin_amdgcn_mfma_f64_16x16x4f64(a2, b1, acc[2][1], 0, 0, 0);
                    acc[3][0] = __builtin_amdgcn_mfma_f64_16x16x4f64(a3, b0, acc[3][0], 0, 0, 0);
                    acc[3][1] = __builtin_amdgcn_mfma_f64_16x16x4f64(a3, b1, acc[3][1], 0, 0, 0);
                }
            }
        }
        // ---- commit prefetched regs to the other buffer, one barrier ----
        if (c + 1 < NCHUNK) {
#pragma unroll
            for (int ci = 0; ci < CI_CHUNK; ++ci) {
                s_in[buf ^ 1][ci * CH + tid] = rin[ci][0];
                if (tid < CELLS - 256) s_in[buf ^ 1][ci * CH + tid + 256] = rin[ci][1];
            }
#pragma unroll
            for (int s = 0; s < 9; ++s) s_w[buf ^ 1][lwoff[s]] = (double)rwt[s];
            __syncthreads();
        }
    }

    // ---- epilogue: bias (f64) -> relu (f32) -> 2x2 maxpool -> store.
    // Reg r of acc[m][n] holds pre-pool x = x0 + xh*16 + 4r + l4, y = y0+2wv+dy.
    // Vertical pool intra-thread (m pairs); horizontal partner x^1 = lane^16.
    const int yp = (y0 >> 1) + wv;
#pragma unroll
    for (int n = 0; n < 2; ++n) {
        const int co = cob * 32 + n * 16 + l15;
        const double bd = (double)bias[co];
        float* orow = out + (((size_t)b * Cout + co) * Hp + yp) * Wp;
#pragma unroll
        for (int xh = 0; xh < 2; ++xh) {
#pragma unroll
            for (int r = 0; r < 4; ++r) {
                const float e0 = fmaxf((float)(acc[xh][n][r]     + bd), 0.f);
                const float e1 = fmaxf((float)(acc[2 + xh][n][r] + bd), 0.f);
                float v = fmaxf(e0, e1);                 // vertical pool
                const float p = __shfl_xor(v, 16, 64);   // horizontal partner
                v = fmaxf(v, p);
                if ((l4 & 1) == 0) {
                    const int xp = (x0 >> 1) + xh * 8 + 2 * r + (l4 >> 1);
                    orow[xp] = v;
                }
            }
        }
    }
}

// ---------------------------------------------------------------------------
// Head 1x1 conv (256->5, f64) + decode (f64) -> boxes/scores. 32 blocks.
// ---------------------------------------------------------------------------
__launch_bounds__(256)
__global__ void head_decode_k(const float* __restrict__ x4,
                              const float* __restrict__ wh,
                              const float* __restrict__ bh,
                              float* __restrict__ boxes,
                              float* __restrict__ scores) {
    __shared__ float s_wh[5 * 256];
    const int tid = threadIdx.x;
#pragma unroll
    for (int i = 0; i < 5; ++i) s_wh[i * 256 + tid] = wh[i * 256 + tid];
    __syncthreads();

    const int idx  = blockIdx.x * 256 + tid;  // 0..8191
    const int b    = idx >> 10;
    const int cell = idx & 1023;
    const int gy = cell >> 5, gx = cell & 31;

    double a0 = (double)bh[0], a1 = (double)bh[1], a2 = (double)bh[2],
           a3 = (double)bh[3], a4 = (double)bh[4];
    const float* xp = x4 + b * 262144 + cell;
    for (int ci = 0; ci < 256; ++ci) {
        const double v = (double)xp[ci << 10];
        a0 = fma(v, (double)s_wh[0 * 256 + ci], a0);
        a1 = fma(v, (double)s_wh[1 * 256 + ci], a1);
        a2 = fma(v, (double)s_wh[2 * 256 + ci], a2);
        a3 = fma(v, (double)s_wh[3 * 256 + ci], a3);
        a4 = fma(v, (double)s_wh[4 * 256 + ci], a4);
    }
    const double obj = 1.0 / (1.0 + exp(-a0));
    const double txs = 1.0 / (1.0 + exp(-a1));
    const double tys = 1.0 / (1.0 + exp(-a2));
    const double bw  = exp(a3) * 16.0;
    const double bhh = exp(a4) * 16.0;
    const double cx  = gx * 16.0 + txs * 16.0;
    const double cy  = gy * 16.0 + tys * 16.0;
    float* bp = boxes + idx * 4;
    bp[0] = (float)fmin(fmax(cx - bw * 0.5, 0.0), 511.0);
    bp[1] = (float)fmin(fmax(cy - bhh * 0.5, 0.0), 511.0);
    bp[2] = (float)fmin(fmax(cx + bw * 0.5, 0.0), 511.0);
    bp[3] = (float)fmin(fmax(cy + bhh * 0.5, 0.0), 511.0);
    scores[idx] = (float)obj;
}

// ---------------------------------------------------------------------------
// Per-batch top-200 (bitonic, lax.top_k tie semantics) + greedy NMS + output.
// ---------------------------------------------------------------------------
__launch_bounds__(256)
__global__ void topk_nms_k(const float* __restrict__ boxes,
                           const float* __restrict__ scores,
                           float* __restrict__ out5,
                           float* __restrict__ keep_out) {
    const int b = blockIdx.x, tid = threadIdx.x;
    __shared__ unsigned long long key[1024];
    __shared__ float bx1[TOPK_N], by1[TOPK_N], bx2[TOPK_N], by2[TOPK_N];
    __shared__ float sv[TOPK_N], ar[TOPK_N];
    __shared__ int   kp[TOPK_N];

    for (int i = tid; i < 1024; i += 256) {
        float s = scores[b * 1024 + i];
        float m = (s >= 0.01f) ? s : -1.0f;
        unsigned u = __float_as_uint(m);
        u = (u & 0x80000000u) ? ~u : (u | 0x80000000u);
        key[i] = ((unsigned long long)u << 32) | (unsigned)(1023 - i);
    }
    __syncthreads();

    for (int k = 2; k <= 1024; k <<= 1) {
        for (int j = k >> 1; j > 0; j >>= 1) {
            for (int i = tid; i < 1024; i += 256) {
                int l = i ^ j;
                if (l > i) {
                    unsigned long long a = key[i], c = key[l];
                    bool desc = ((i & k) == 0);
                    bool sw = desc ? (a < c) : (a > c);
                    if (sw) { key[i] = c; key[l] = a; }
                }
            }
            __syncthreads();
        }
    }

    for (int i = tid; i < TOPK_N; i += 256) {
        unsigned long long kk = key[i];
        unsigned u = (unsigned)(kk >> 32);
        unsigned bits = (u & 0x80000000u) ? (u & 0x7FFFFFFFu) : ~u;
        float s = __uint_as_float(bits);
        int src = 1023 - (int)(kk & 0xFFFFFFFFu);
        const float4 bb = *(const float4*)(boxes + (b * 1024 + src) * 4);
        bx1[i] = bb.x; by1[i] = bb.y; bx2[i] = bb.z; by2[i] = bb.w;
        sv[i] = s;
        ar[i] = (bb.z - bb.x) * (bb.w - bb.y);
        kp[i] = (s >= 0.01f) ? 1 : 0;
    }
    __syncthreads();

    for (int i = 0; i < TOPK_N; ++i) {
        if (kp[i]) {
            const float X1 = bx1[i], Y1 = by1[i], X2 = bx2[i], Y2 = by2[i], A = ar[i];
            for (int j = tid; j < TOPK_N; j += 256) {
                if (j > i && kp[j]) {
                    float xx1 = fmaxf(X1, bx1[j]);
                    float yy1 = fmaxf(Y1, by1[j]);
                    float xx2 = fminf(X2, bx2[j]);
                    float yy2 = fminf(Y2, by2[j]);
                    float inter = fmaxf(xx2 - xx1, 0.f) * fmaxf(yy2 - yy1, 0.f);
                    float uni = A + ar[j] - inter;
                    float iou = inter / fmaxf(uni, 1e-6f);
                    if (iou > 0.5f) kp[j] = 0;
                }
            }
        }
        __syncthreads();
    }

    for (int i = tid; i < TOPK_N; i += 256) {
        float kf = kp[i] ? 1.f : 0.f;
        float s  = sv[i];
        float sc = (s >= 0.01f) ? s : 0.f;
        float* op = out5 + (b * TOPK_N + i) * 5;
        op[0] = bx1[i] * kf;
        op[1] = by1[i] * kf;
        op[2] = bx2[i] * kf;
        op[3] = by2[i] * kf;
        op[4] = sc * kf;
        keep_out[b * TOPK_N + i] = kf;
    }
}

extern "C" void kernel_launch(void* const* d_in, const int* in_sizes, int n_in,
                              void* d_out, int out_size, void* d_ws, size_t ws_size,
                              hipStream_t stream) {
    const float* images = (const float*)d_in[0];
    const float* w1 = (const float*)d_in[1];
    const float* b1 = (const float*)d_in[2];
    const float* w2 = (const float*)d_in[3];
    const float* b2 = (const float*)d_in[4];
    const float* w3 = (const float*)d_in[5];
    const float* b3 = (const float*)d_in[6];
    const float* w4 = (const float*)d_in[7];
    const float* b4 = (const float*)d_in[8];
    const float* wh = (const float*)d_in[9];
    const float* bh = (const float*)d_in[10];
    float* out = (float*)d_out;

    float* A    = (float*)d_ws;          // x1 [8,32,256,256] -> x3 [8,128,64,64]
    float* Bbuf = A + 16777216;          // x2 [8,64,128,128] -> x4 [8,256,32,32]
    float* boxes  = A + 8388608;         // dead x1 space: 32768 floats
    float* scores = A + 8388608 + 32768; //  8192 floats

    // L1: 3->32, 512x512 -> 256x256. VALU-f64 template (CIN=3 not mfma-shaped).
    conv_relu_pool_pipe<3, 3, 8><<<dim3(16, 16, 8 * 4), 256, 0, stream>>>(
        images, w1, b1, A, 512, 512, 32);
    // L2: 32->64, 256x256 in. MFMA-f64: grid (Wpre/32, Hpre/8, B*Cout/32).
    conv_mfma_f64<32><<<dim3(8, 32, 8 * 2), 256, 0, stream>>>(
        A, w2, b2, Bbuf, 256, 256, 64);
    // L3: 64->128, 128x128 in.
    conv_mfma_f64<64><<<dim3(4, 16, 8 * 4), 256, 0, stream>>>(
        Bbuf, w3, b3, A, 128, 128, 128);
    // L4: 128->256, 64x64 in.
    conv_mfma_f64<128><<<dim3(2, 8, 8 * 8), 256, 0, stream>>>(
        A, w4, b4, Bbuf, 64, 64, 256);
    // Head + decode: 32 blocks, coalesced
    head_decode_k<<<32, 256, 0, stream>>>(Bbuf, wh, bh, boxes, scores);
    // Top-k + NMS + output
    topk_nms_k<<<8, 256, 0, stream>>>(boxes, scores, out, out + 8 * TOPK_N * 5);
}